// Round 1
// baseline (1807.185 us; speedup 1.0000x reference)
//
#include <hip/hip_runtime.h>
#include <hip/hip_bf16.h>

#define TOKENS 32768
#define DIM    512
#define KCODES 4096

// argmin kernel tiling
#define TT   128   // tokens per block
#define CT   256   // codes per tile
#define DC   32    // d-chunk staged in LDS
#define XPAD 132   // row stride for xs (16B-aligned: 132*4=528=33*16)
#define CPAD 260   // row stride for cs (260*4=1040=65*16)

// ---------------------------------------------------------------------------
// Row-wise sum of squares with fp64 accumulation (exact products, ~exact sum),
// rounded once to fp32. One wave (64 lanes) per row, D=512.
// ---------------------------------------------------------------------------
__global__ void rowsumsq_kernel(const float* __restrict__ in,
                                float* __restrict__ out, int nrows) {
  int wave = (int)((blockIdx.x * (size_t)blockDim.x + threadIdx.x) >> 6);
  int lane = threadIdx.x & 63;
  if (wave >= nrows) return;
  const float4* r = reinterpret_cast<const float4*>(in + (size_t)wave * DIM);
  float4 a = r[lane];        // d = lane*4 .. +3      (0..255)
  float4 b = r[lane + 64];   // d = 256 + lane*4 ..   (256..511)
  double acc = (double)a.x * a.x + (double)a.y * a.y +
               (double)a.z * a.z + (double)a.w * a.w +
               (double)b.x * b.x + (double)b.y * b.y +
               (double)b.z * b.z + (double)b.w * b.w;
  #pragma unroll
  for (int off = 32; off; off >>= 1) acc += __shfl_xor(acc, off, 64);
  if (lane == 0) out[wave] = (float)acc;
}

// ---------------------------------------------------------------------------
// Fused distance GEMM + argmin. Each block: 128 tokens x all 4096 codes.
// d_k = fl(fl(x_sq - 2*dot) + c_sq_k), argmin with lowest-index tie-break,
// replicating the reference's fp32 rounding structure.
// ---------------------------------------------------------------------------
__global__ __launch_bounds__(512, 2) void argmin_kernel(
    const float* __restrict__ X, const float* __restrict__ CB,
    const float* __restrict__ xsq, const float* __restrict__ csq,
    float* __restrict__ idx_out) {
  __shared__ float xs[DC][XPAD];
  __shared__ float cs[DC][CPAD];
  __shared__ float red_d[TT][33];
  __shared__ int   red_i[TT][33];

  const int tid = threadIdx.x;
  const int tx  = tid & 31;   // code group   (8 codes each)
  const int ty  = tid >> 5;   // token group  (8 tokens each)
  const size_t row0 = (size_t)blockIdx.x * TT;

  float xsq_r[8];
  #pragma unroll
  for (int i = 0; i < 8; ++i) xsq_r[i] = xsq[row0 + ty * 8 + i];

  float best_d[8];
  int   best_i[8];
  #pragma unroll
  for (int i = 0; i < 8; ++i) { best_d[i] = 3.4e38f; best_i[i] = 0; }

  // staging thread mapping
  const int xtk = tid >> 2;  // 0..127 token within tile
  const int xq  = tid & 3;   // 0..3
  const int cck = tid >> 1;  // 0..255 code within tile
  const int ch  = tid & 1;   // 0..1

  for (int ct = 0; ct < KCODES / CT; ++ct) {
    const int code0 = ct * CT;
    float acc[8][8];
    #pragma unroll
    for (int i = 0; i < 8; ++i)
      #pragma unroll
      for (int j = 0; j < 8; ++j) acc[i][j] = 0.0f;

    for (int dc = 0; dc < DIM / DC; ++dc) {
      const int d0 = dc * DC;
      __syncthreads();  // protect previous iteration's reads
      {  // stage x tile (transposed): xs[k][token]
        const float4* src =
            reinterpret_cast<const float4*>(X + (row0 + xtk) * DIM + d0);
        float4 A = src[xq];
        float4 B = src[xq + 4];
        xs[xq * 4 + 0][xtk] = A.x;  xs[xq * 4 + 1][xtk] = A.y;
        xs[xq * 4 + 2][xtk] = A.z;  xs[xq * 4 + 3][xtk] = A.w;
        xs[16 + xq * 4 + 0][xtk] = B.x;  xs[16 + xq * 4 + 1][xtk] = B.y;
        xs[16 + xq * 4 + 2][xtk] = B.z;  xs[16 + xq * 4 + 3][xtk] = B.w;
      }
      {  // stage c tile (transposed): cs[k][code]
        const float4* src = reinterpret_cast<const float4*>(
            CB + (size_t)(code0 + cck) * DIM + d0 + ch * 16);
        float4 A = src[0], B = src[1], C = src[2], D4 = src[3];
        const int kb = ch * 16;
        cs[kb + 0][cck] = A.x;   cs[kb + 1][cck] = A.y;
        cs[kb + 2][cck] = A.z;   cs[kb + 3][cck] = A.w;
        cs[kb + 4][cck] = B.x;   cs[kb + 5][cck] = B.y;
        cs[kb + 6][cck] = B.z;   cs[kb + 7][cck] = B.w;
        cs[kb + 8][cck] = C.x;   cs[kb + 9][cck] = C.y;
        cs[kb + 10][cck] = C.z;  cs[kb + 11][cck] = C.w;
        cs[kb + 12][cck] = D4.x; cs[kb + 13][cck] = D4.y;
        cs[kb + 14][cck] = D4.z; cs[kb + 15][cck] = D4.w;
      }
      __syncthreads();
      #pragma unroll 8
      for (int k = 0; k < DC; ++k) {
        const float4* xr = reinterpret_cast<const float4*>(&xs[k][ty * 8]);
        float4 xa = xr[0], xb = xr[1];
        const float4* cr = reinterpret_cast<const float4*>(&cs[k][tx * 8]);
        float4 ca = cr[0], cb4 = cr[1];
        float xv[8] = {xa.x, xa.y, xa.z, xa.w, xb.x, xb.y, xb.z, xb.w};
        float cv[8] = {ca.x, ca.y, ca.z, ca.w, cb4.x, cb4.y, cb4.z, cb4.w};
        #pragma unroll
        for (int i = 0; i < 8; ++i)
          #pragma unroll
          for (int j = 0; j < 8; ++j)
            acc[i][j] = fmaf(xv[i], cv[j], acc[i][j]);
      }
    }
    // per-tile argmin epilogue (replicate ref rounding exactly)
    float cs_j[8];
    {
      const float4* cq = reinterpret_cast<const float4*>(csq + code0 + tx * 8);
      float4 q0 = cq[0], q1 = cq[1];
      cs_j[0] = q0.x; cs_j[1] = q0.y; cs_j[2] = q0.z; cs_j[3] = q0.w;
      cs_j[4] = q1.x; cs_j[5] = q1.y; cs_j[6] = q1.z; cs_j[7] = q1.w;
    }
    #pragma unroll
    for (int i = 0; i < 8; ++i) {
      #pragma unroll
      for (int j = 0; j < 8; ++j) {
        float dist = xsq_r[i] - 2.0f * acc[i][j];  // 2*m exact; one rounding
        dist = dist + cs_j[j];                     // second rounding
        int idx = code0 + tx * 8 + j;              // ascending within thread
        if (dist < best_d[i]) { best_d[i] = dist; best_i[i] = idx; }
      }
    }
  }

  __syncthreads();
  #pragma unroll
  for (int i = 0; i < 8; ++i) {
    red_d[ty * 8 + i][tx] = best_d[i];
    red_i[ty * 8 + i][tx] = best_i[i];
  }
  __syncthreads();
  if (tid < TT) {
    float bd = red_d[tid][0];
    int   bi = red_i[tid][0];
    #pragma unroll 4
    for (int t = 1; t < 32; ++t) {
      float d = red_d[tid][t];
      int  ii = red_i[tid][t];
      if (d < bd || (d == bd && ii < bi)) { bd = d; bi = ii; }
    }
    idx_out[row0 + tid] = (float)bi;
  }
}

// ---------------------------------------------------------------------------
__global__ void zero_kernel(float* __restrict__ p, int n) {
  int i = blockIdx.x * blockDim.x + threadIdx.x;
  if (i < n) p[i] = 0.0f;
}

__global__ void count_kernel(const float* __restrict__ idxf,
                             float* __restrict__ counts) {
  int t = blockIdx.x * blockDim.x + threadIdx.x;
  if (t < TOKENS) atomicAdd(&counts[(int)idxf[t]], 1.0f);
}

__global__ void ema_kernel(const float* __restrict__ cc,
                           const float* __restrict__ counts,
                           float* __restrict__ out) {
  int k = blockIdx.x * blockDim.x + threadIdx.x;
  if (k < KCODES) out[k] = 0.99f * cc[k] + 0.01f * counts[k];
}

// quantized_ste = fl(x + fl(q - x)); loss = fl(s + fl(0.25*s)), s = fl((q-x)^2)
__global__ void output_kernel(const float* __restrict__ X,
                              const float* __restrict__ CB,
                              const float* __restrict__ idxf,
                              float* __restrict__ out0,
                              float* __restrict__ out1) {
  int g = blockIdx.x * blockDim.x + threadIdx.x;  // float4 index
  if (g >= TOKENS * DIM / 4) return;
  int token = g >> 7;  // 128 float4 per token
  int idx = (int)idxf[token];
  float4 x4 = reinterpret_cast<const float4*>(X)[g];
  float4 q4 = reinterpret_cast<const float4*>(CB)[(size_t)idx * 128 + (g & 127)];
  float4 o0, o1;
  {
    float d;
    d = q4.x - x4.x; o0.x = x4.x + d; { float s = d * d; o1.x = s + 0.25f * s; }
    d = q4.y - x4.y; o0.y = x4.y + d; { float s = d * d; o1.y = s + 0.25f * s; }
    d = q4.z - x4.z; o0.z = x4.z + d; { float s = d * d; o1.z = s + 0.25f * s; }
    d = q4.w - x4.w; o0.w = x4.w + d; { float s = d * d; o1.w = s + 0.25f * s; }
  }
  reinterpret_cast<float4*>(out0)[g] = o0;
  reinterpret_cast<float4*>(out1)[g] = o1;
}

// ---------------------------------------------------------------------------
extern "C" void kernel_launch(void* const* d_in, const int* in_sizes, int n_in,
                              void* d_out, int out_size, void* d_ws,
                              size_t ws_size, hipStream_t stream) {
  const float* X  = (const float*)d_in[0];  // [32768, 512]
  const float* CB = (const float*)d_in[1];  // [4096, 512]
  const float* CC = (const float*)d_in[2];  // [4096]

  float* o = (float*)d_out;
  float* out0 = o;                       // quantized_ste  16777216
  float* out1 = o + 16777216;            // quant_loss     16777216
  float* out2 = o + 33554432;            // nn_idx (float) 32768
  float* out3 = o + 33587200;            // codebook copy  2097152
  float* out4 = o + 35684352;            // new counts     4096

  float* ws_xsq    = (float*)d_ws;          // 32768
  float* ws_csq    = ws_xsq + TOKENS;       // 4096
  float* ws_counts = ws_csq + KCODES;       // 4096

  rowsumsq_kernel<<<TOKENS / 4, 256, 0, stream>>>(X, ws_xsq, TOKENS);
  rowsumsq_kernel<<<KCODES / 4, 256, 0, stream>>>(CB, ws_csq, KCODES);
  zero_kernel<<<(KCODES + 255) / 256, 256, 0, stream>>>(ws_counts, KCODES);

  argmin_kernel<<<TOKENS / TT, 512, 0, stream>>>(X, CB, ws_xsq, ws_csq, out2);

  count_kernel<<<TOKENS / 256, 256, 0, stream>>>(out2, ws_counts);
  ema_kernel<<<(KCODES + 255) / 256, 256, 0, stream>>>(CC, ws_counts, out4);
  output_kernel<<<(TOKENS * DIM / 4 + 255) / 256, 256, 0, stream>>>(
      X, CB, out2, out0, out1);
  hipMemcpyAsync(out3, CB, (size_t)KCODES * DIM * sizeof(float),
                 hipMemcpyDeviceToDevice, stream);
}

// Round 2
// 1202.297 us; speedup vs baseline: 1.5031x; 1.5031x over previous
//
#include <hip/hip_runtime.h>

typedef __attribute__((ext_vector_type(8))) short short8v;
typedef __attribute__((ext_vector_type(4))) float f32x4;
typedef __attribute__((ext_vector_type(8))) unsigned short ushort8v;

#define TOKENS 32768
#define DIM    512
#define KCODES 4096
#define CSPLIT 4
#define CT_PER 8   // 128-code tiles per block: (4096/CSPLIT)/128

// ---------------------------------------------------------------------------
// bf16 helpers (RNE, matches __float2bfloat16 semantics; inputs are finite)
// ---------------------------------------------------------------------------
__device__ __forceinline__ unsigned short f2bf(float f) {
  unsigned int u = __builtin_bit_cast(unsigned int, f);
  u += 0x7fffu + ((u >> 16) & 1u);
  return (unsigned short)(u >> 16);
}
__device__ __forceinline__ float bf2f(unsigned short h) {
  unsigned int u = ((unsigned int)h) << 16;
  return __builtin_bit_cast(float, u);
}

typedef const __attribute__((address_space(1))) void* gvoidp;
typedef __attribute__((address_space(3))) void* lvoidp;
#define GLOAD16(g, l) \
  __builtin_amdgcn_global_load_lds((gvoidp)(g), (lvoidp)(l), 16, 0, 0)

// ---------------------------------------------------------------------------
// Split fp32 -> (bf16 hi, bf16 lo residual). 8 elems/thread, vector stores.
// ---------------------------------------------------------------------------
__global__ void split_kernel(const float* __restrict__ in,
                             unsigned short* __restrict__ hi,
                             unsigned short* __restrict__ lo, int n8) {
  int g = blockIdx.x * blockDim.x + threadIdx.x;
  if (g >= n8) return;
  const float4* p = (const float4*)in + (size_t)g * 2;
  float4 a = p[0], b = p[1];
  float x[8] = {a.x, a.y, a.z, a.w, b.x, b.y, b.z, b.w};
  ushort8v hv, lv;
#pragma unroll
  for (int j = 0; j < 8; ++j) {
    unsigned short h = f2bf(x[j]);
    hv[j] = h;
    lv[j] = f2bf(x[j] - bf2f(h));
  }
  ((ushort8v*)hi)[g] = hv;
  ((ushort8v*)lo)[g] = lv;
}

// ---------------------------------------------------------------------------
// Row-wise sum of squares, fp64 accumulation, one wave per row (D=512).
// ---------------------------------------------------------------------------
__global__ void rowsumsq_kernel(const float* __restrict__ in,
                                float* __restrict__ out, int nrows) {
  int wave = (int)((blockIdx.x * (size_t)blockDim.x + threadIdx.x) >> 6);
  int lane = threadIdx.x & 63;
  if (wave >= nrows) return;
  const float4* r = reinterpret_cast<const float4*>(in + (size_t)wave * DIM);
  float4 a = r[lane];
  float4 b = r[lane + 64];
  double acc = (double)a.x * a.x + (double)a.y * a.y +
               (double)a.z * a.z + (double)a.w * a.w +
               (double)b.x * b.x + (double)b.y * b.y +
               (double)b.z * b.z + (double)b.w * b.w;
#pragma unroll
  for (int off = 32; off; off >>= 1) acc += __shfl_xor(acc, off, 64);
  if (lane == 0) out[wave] = (float)acc;
}

// ---------------------------------------------------------------------------
// One K=512 phase of the 3-term split GEMM: acc += A(tokens)·B(codes)^T
// m97-style: 128x128 tile, BK=64, linear LDS, global_load_lds x16, 2 barriers.
// ---------------------------------------------------------------------------
__device__ __forceinline__ void k_phase(
    const unsigned short* __restrict__ xp, const unsigned short* __restrict__ cp,
    int row0, int code0, short* As, short* Bs, f32x4 (&acc)[4][4],
    int wid, int lane, int g16, int l15, int wr, int wc) {
  for (int dc = 0; dc < 8; ++dc) {
    const int d0 = dc * 64;
    __syncthreads();  // previous step's LDS reads complete
#pragma unroll
    for (int i = 0; i < 4; ++i) {
      const int cb = i * 256 + wid * 64;  // wave-uniform chunk base
      const int ck = cb + lane;           // this lane's 16B chunk
      const int r = ck >> 3, kc = ck & 7;
      GLOAD16(xp + (size_t)(row0 + r) * DIM + d0 + kc * 8, As + cb * 8);
      GLOAD16(cp + (size_t)(code0 + r) * DIM + d0 + kc * 8, Bs + cb * 8);
    }
    __syncthreads();  // staging complete (vmcnt drained by barrier)
#pragma unroll
    for (int kk = 0; kk < 2; ++kk) {
      const int ko = kk * 32 + g16 * 8;
      short8v a[4], b[4];
#pragma unroll
      for (int m = 0; m < 4; ++m)
        a[m] = *(const short8v*)(As + (wr * 64 + m * 16 + l15) * 64 + ko);
#pragma unroll
      for (int n = 0; n < 4; ++n)
        b[n] = *(const short8v*)(Bs + (wc * 64 + n * 16 + l15) * 64 + ko);
#pragma unroll
      for (int m = 0; m < 4; ++m)
#pragma unroll
        for (int n = 0; n < 4; ++n)
          acc[m][n] = __builtin_amdgcn_mfma_f32_16x16x32_bf16(a[m], b[n],
                                                              acc[m][n], 0, 0, 0);
    }
  }
}

// ---------------------------------------------------------------------------
// Fused split-bf16 distance GEMM + argmin over a 1024-code slice.
// dist = fl(fl(xsq - 2*dot) + csq), lowest-index tie-break.
// ---------------------------------------------------------------------------
__global__ __launch_bounds__(256) void argmin_mfma_kernel(
    const unsigned short* __restrict__ Xh, const unsigned short* __restrict__ Xl,
    const unsigned short* __restrict__ Ch, const unsigned short* __restrict__ Cl,
    const float* __restrict__ xsq, const float* __restrict__ csq,
    float* __restrict__ pd, float* __restrict__ pi) {
  __shared__ short As[128 * 64];
  __shared__ short Bs[128 * 64];
  __shared__ float red_d[2][128];
  __shared__ int   red_i[2][128];

  const int tid  = threadIdx.x;
  const int wid  = tid >> 6;
  const int lane = tid & 63;
  const int wr = wid >> 1, wc = wid & 1;
  const int g16 = lane >> 4, l15 = lane & 15;
  const int row0  = blockIdx.x * 128;
  const int cbase = blockIdx.y * (KCODES / CSPLIT);

  float xsq_r[4][4];
#pragma unroll
  for (int m = 0; m < 4; ++m)
#pragma unroll
    for (int r = 0; r < 4; ++r)
      xsq_r[m][r] = xsq[row0 + wr * 64 + m * 16 + g16 * 4 + r];

  float best_d[4][4];
  int   best_i[4][4];
#pragma unroll
  for (int m = 0; m < 4; ++m)
#pragma unroll
    for (int r = 0; r < 4; ++r) { best_d[m][r] = 3.4e38f; best_i[m][r] = 0; }

  for (int ct = 0; ct < CT_PER; ++ct) {
    const int code0 = cbase + ct * 128;
    f32x4 acc[4][4];
#pragma unroll
    for (int m = 0; m < 4; ++m)
#pragma unroll
      for (int n = 0; n < 4; ++n) {
        acc[m][n][0] = 0.f; acc[m][n][1] = 0.f;
        acc[m][n][2] = 0.f; acc[m][n][3] = 0.f;
      }

    // dot = Xh·Ch + Xh·Cl + Xl·Ch   (K_eff = 1536)
    k_phase(Xh, Ch, row0, code0, As, Bs, acc, wid, lane, g16, l15, wr, wc);
    k_phase(Xh, Cl, row0, code0, As, Bs, acc, wid, lane, g16, l15, wr, wc);
    k_phase(Xl, Ch, row0, code0, As, Bs, acc, wid, lane, g16, l15, wr, wc);

    float cs_r[4];
#pragma unroll
    for (int n = 0; n < 4; ++n) cs_r[n] = csq[code0 + wc * 64 + n * 16 + l15];
#pragma unroll
    for (int m = 0; m < 4; ++m)
#pragma unroll
      for (int n = 0; n < 4; ++n) {
        const int code = code0 + wc * 64 + n * 16 + l15;
#pragma unroll
        for (int r = 0; r < 4; ++r) {
          float dist = xsq_r[m][r] - 2.0f * acc[m][n][r];
          dist += cs_r[n];
          if (dist < best_d[m][r]) { best_d[m][r] = dist; best_i[m][r] = code; }
        }
      }
  }

  // 16-lane (code-dim) reduction with lowest-index tie-break
#pragma unroll
  for (int m = 0; m < 4; ++m)
#pragma unroll
    for (int r = 0; r < 4; ++r) {
      float d = best_d[m][r];
      int   bi = best_i[m][r];
#pragma unroll
      for (int off = 1; off < 16; off <<= 1) {
        float od = __shfl_xor(d, off, 64);
        int   oi = __shfl_xor(bi, off, 64);
        if (od < d || (od == d && oi < bi)) { d = od; bi = oi; }
      }
      if (l15 == 0) {
        const int tl = wr * 64 + m * 16 + g16 * 4 + r;
        red_d[wc][tl] = d;
        red_i[wc][tl] = bi;
      }
    }
  __syncthreads();
  if (tid < 128) {
    float da = red_d[0][tid], db = red_d[1][tid];
    int   ia = red_i[0][tid], ib = red_i[1][tid];
    bool take_b = (db < da) || (db == da && ib < ia);
    pd[blockIdx.y * TOKENS + row0 + tid] = take_b ? db : da;
    pi[blockIdx.y * TOKENS + row0 + tid] = (float)(take_b ? ib : ia);
  }
}

// ---------------------------------------------------------------------------
__global__ void merge_kernel(const float* __restrict__ pd,
                             const float* __restrict__ pi,
                             float* __restrict__ out_idx) {
  int t = blockIdx.x * blockDim.x + threadIdx.x;
  if (t >= TOKENS) return;
  float bd = pd[t];
  float bi = pi[t];
#pragma unroll
  for (int y = 1; y < CSPLIT; ++y) {
    float d = pd[y * TOKENS + t], ii = pi[y * TOKENS + t];
    if (d < bd || (d == bd && ii < bi)) { bd = d; bi = ii; }
  }
  out_idx[t] = bi;
}

__global__ void zero_kernel(float* __restrict__ p, int n) {
  int i = blockIdx.x * blockDim.x + threadIdx.x;
  if (i < n) p[i] = 0.0f;
}

__global__ void count_kernel(const float* __restrict__ idxf,
                             float* __restrict__ counts) {
  int t = blockIdx.x * blockDim.x + threadIdx.x;
  if (t < TOKENS) atomicAdd(&counts[(int)idxf[t]], 1.0f);
}

__global__ void ema_kernel(const float* __restrict__ cc,
                           const float* __restrict__ counts,
                           float* __restrict__ out) {
  int k = blockIdx.x * blockDim.x + threadIdx.x;
  if (k < KCODES) out[k] = 0.99f * cc[k] + 0.01f * counts[k];
}

__global__ void output_kernel(const float* __restrict__ X,
                              const float* __restrict__ CB,
                              const float* __restrict__ idxf,
                              float* __restrict__ out0,
                              float* __restrict__ out1) {
  int g = blockIdx.x * blockDim.x + threadIdx.x;  // float4 index
  if (g >= TOKENS * DIM / 4) return;
  int token = g >> 7;
  int idx = (int)idxf[token];
  float4 x4 = reinterpret_cast<const float4*>(X)[g];
  float4 q4 = reinterpret_cast<const float4*>(CB)[(size_t)idx * 128 + (g & 127)];
  float4 o0, o1;
  {
    float d;
    d = q4.x - x4.x; o0.x = x4.x + d; { float s = d * d; o1.x = s + 0.25f * s; }
    d = q4.y - x4.y; o0.y = x4.y + d; { float s = d * d; o1.y = s + 0.25f * s; }
    d = q4.z - x4.z; o0.z = x4.z + d; { float s = d * d; o1.z = s + 0.25f * s; }
    d = q4.w - x4.w; o0.w = x4.w + d; { float s = d * d; o1.w = s + 0.25f * s; }
  }
  reinterpret_cast<float4*>(out0)[g] = o0;
  reinterpret_cast<float4*>(out1)[g] = o1;
}

// ---------------------------------------------------------------------------
extern "C" void kernel_launch(void* const* d_in, const int* in_sizes, int n_in,
                              void* d_out, int out_size, void* d_ws,
                              size_t ws_size, hipStream_t stream) {
  const float* X  = (const float*)d_in[0];  // [32768, 512]
  const float* CB = (const float*)d_in[1];  // [4096, 512]
  const float* CC = (const float*)d_in[2];  // [4096]

  float* o = (float*)d_out;
  float* out0 = o;               // quantized_ste  16777216
  float* out1 = o + 16777216;    // quant_loss     16777216
  float* out2 = o + 33554432;    // nn_idx (float) 32768
  float* out3 = o + 33587200;    // codebook copy  2097152
  float* out4 = o + 35684352;    // new counts     4096

  // bf16 staging lives in the out0/out1 regions (128 MB), which are only
  // written by output_kernel at the very end.
  unsigned short* Xh = (unsigned short*)d_out;
  unsigned short* Xl = Xh + (size_t)TOKENS * DIM;
  unsigned short* Chp = Xl + (size_t)TOKENS * DIM;
  unsigned short* Clp = Chp + (size_t)KCODES * DIM;
  float* pd = (float*)(Clp + (size_t)KCODES * DIM);  // [CSPLIT][TOKENS]
  float* pi = pd + TOKENS * CSPLIT;                  // [CSPLIT][TOKENS]

  float* ws_xsq    = (float*)d_ws;          // 32768
  float* ws_csq    = ws_xsq + TOKENS;       // 4096
  float* ws_counts = ws_csq + KCODES;       // 4096

  split_kernel<<<TOKENS * DIM / 8 / 256, 256, 0, stream>>>(X, Xh, Xl,
                                                           TOKENS * DIM / 8);
  split_kernel<<<KCODES * DIM / 8 / 256, 256, 0, stream>>>(CB, Chp, Clp,
                                                           KCODES * DIM / 8);
  rowsumsq_kernel<<<TOKENS / 4, 256, 0, stream>>>(X, ws_xsq, TOKENS);
  rowsumsq_kernel<<<KCODES / 4, 256, 0, stream>>>(CB, ws_csq, KCODES);
  zero_kernel<<<(KCODES + 255) / 256, 256, 0, stream>>>(ws_counts, KCODES);

  dim3 grid(TOKENS / 128, CSPLIT);
  argmin_mfma_kernel<<<grid, 256, 0, stream>>>(Xh, Xl, Chp, Clp, ws_xsq,
                                               ws_csq, pd, pi);
  merge_kernel<<<TOKENS / 256, 256, 0, stream>>>(pd, pi, out2);

  count_kernel<<<TOKENS / 256, 256, 0, stream>>>(out2, ws_counts);
  ema_kernel<<<(KCODES + 255) / 256, 256, 0, stream>>>(CC, ws_counts, out4);
  output_kernel<<<(TOKENS * DIM / 4 + 255) / 256, 256, 0, stream>>>(
      X, CB, out2, out0, out1);
  hipMemcpyAsync(out3, CB, (size_t)KCODES * DIM * sizeof(float),
                 hipMemcpyDeviceToDevice, stream);
}

// Round 3
// 790.843 us; speedup vs baseline: 2.2851x; 1.5203x over previous
//
#include <hip/hip_runtime.h>

typedef __attribute__((ext_vector_type(8))) short short8v;
typedef __attribute__((ext_vector_type(4))) float f32x4;
typedef __attribute__((ext_vector_type(8))) unsigned short ushort8v;

#define TOKENS 32768
#define DIM    512
#define KCODES 4096
#define CSPLIT 4
#define CT_PER 8   // 128-code tiles per block: (4096/CSPLIT)/128

// ---------------------------------------------------------------------------
// bf16 helpers (RNE, matches __float2bfloat16 semantics; inputs are finite)
// ---------------------------------------------------------------------------
__device__ __forceinline__ unsigned short f2bf(float f) {
  unsigned int u = __builtin_bit_cast(unsigned int, f);
  u += 0x7fffu + ((u >> 16) & 1u);
  return (unsigned short)(u >> 16);
}
__device__ __forceinline__ float bf2f(unsigned short h) {
  unsigned int u = ((unsigned int)h) << 16;
  return __builtin_bit_cast(float, u);
}

typedef const __attribute__((address_space(1))) void* gvoidp;
typedef __attribute__((address_space(3))) void* lvoidp;
#define GLOAD16(g, l) \
  __builtin_amdgcn_global_load_lds((gvoidp)(g), (lvoidp)(l), 16, 0, 0)

// ---------------------------------------------------------------------------
// Split fp32 -> (bf16 hi, bf16 lo residual). 8 elems/thread, vector stores.
// ---------------------------------------------------------------------------
__global__ void split_kernel(const float* __restrict__ in,
                             unsigned short* __restrict__ hi,
                             unsigned short* __restrict__ lo, int n8) {
  int g = blockIdx.x * blockDim.x + threadIdx.x;
  if (g >= n8) return;
  const float4* p = (const float4*)in + (size_t)g * 2;
  float4 a = p[0], b = p[1];
  float x[8] = {a.x, a.y, a.z, a.w, b.x, b.y, b.z, b.w};
  ushort8v hv, lv;
#pragma unroll
  for (int j = 0; j < 8; ++j) {
    unsigned short h = f2bf(x[j]);
    hv[j] = h;
    lv[j] = f2bf(x[j] - bf2f(h));
  }
  ((ushort8v*)hi)[g] = hv;
  ((ushort8v*)lo)[g] = lv;
}

// ---------------------------------------------------------------------------
// Row-wise sum of squares, fp64 accumulation, one wave per row (D=512).
// ---------------------------------------------------------------------------
__global__ void rowsumsq_kernel(const float* __restrict__ in,
                                float* __restrict__ out, int nrows) {
  int wave = (int)((blockIdx.x * (size_t)blockDim.x + threadIdx.x) >> 6);
  int lane = threadIdx.x & 63;
  if (wave >= nrows) return;
  const float4* r = reinterpret_cast<const float4*>(in + (size_t)wave * DIM);
  float4 a = r[lane];
  float4 b = r[lane + 64];
  double acc = (double)a.x * a.x + (double)a.y * a.y +
               (double)a.z * a.z + (double)a.w * a.w +
               (double)b.x * b.x + (double)b.y * b.y +
               (double)b.z * b.z + (double)b.w * b.w;
#pragma unroll
  for (int off = 32; off; off >>= 1) acc += __shfl_xor(acc, off, 64);
  if (lane == 0) out[wave] = (float)acc;
}

// ---------------------------------------------------------------------------
// Fused split-bf16 distance GEMM + argmin over a 1024-code slice.
// One merged K-pass per 128-code tile: stage Xh/Xl/Ch/Cl 64-wide chunks,
// acc += Xh·Ch + Xh·Cl + Xl·Ch  (K_eff = 1536).
// LDS tiles are chunk-XOR-swizzled: original 16B chunk (r,c) lives at LDS
// slot (r, c^(r&7)); staging pre-swizzles the GLOBAL source column so the
// LDS destination of global_load_lds stays linear (guide rule #21).
// dist = fl(fl(xsq - 2*dot) + csq), lowest-index tie-break.
// ---------------------------------------------------------------------------
__global__ __launch_bounds__(256) void argmin_mfma_kernel(
    const unsigned short* __restrict__ Xh, const unsigned short* __restrict__ Xl,
    const unsigned short* __restrict__ Ch, const unsigned short* __restrict__ Cl,
    const float* __restrict__ xsq, const float* __restrict__ csq,
    float* __restrict__ pd, float* __restrict__ pi) {
  __shared__ short XhS[128 * 64];
  __shared__ short XlS[128 * 64];
  __shared__ short ChS[128 * 64];
  __shared__ short ClS[128 * 64];
  __shared__ float red_d[2][128];
  __shared__ int   red_i[2][128];

  const int tid  = threadIdx.x;
  const int wid  = tid >> 6;
  const int lane = tid & 63;
  const int wr = wid >> 1, wc = wid & 1;
  const int g16 = lane >> 4, l15 = lane & 15;
  const int row0  = blockIdx.x * 128;
  const int cbase = blockIdx.y * (KCODES / CSPLIT);

  float xsq_r[4][4];
#pragma unroll
  for (int m = 0; m < 4; ++m)
#pragma unroll
    for (int r = 0; r < 4; ++r)
      xsq_r[m][r] = xsq[row0 + wr * 64 + m * 16 + g16 * 4 + r];

  float best_d[4][4];
  int   best_i[4][4];
#pragma unroll
  for (int m = 0; m < 4; ++m)
#pragma unroll
    for (int r = 0; r < 4; ++r) { best_d[m][r] = 3.4e38f; best_i[m][r] = 0; }

  for (int ct = 0; ct < CT_PER; ++ct) {
    const int code0 = cbase + ct * 128;
    f32x4 acc[4][4];
#pragma unroll
    for (int m = 0; m < 4; ++m)
#pragma unroll
      for (int n = 0; n < 4; ++n) {
        acc[m][n][0] = 0.f; acc[m][n][1] = 0.f;
        acc[m][n][2] = 0.f; acc[m][n][3] = 0.f;
      }

    for (int dc = 0; dc < 8; ++dc) {
      const int d0 = dc * 64;
      __syncthreads();  // previous step's LDS reads complete
#pragma unroll
      for (int i = 0; i < 4; ++i) {
        const int cb = i * 256 + wid * 64;  // wave-uniform chunk base
        const int ck = cb + lane;           // this lane's linear LDS chunk
        const int r = ck >> 3, c = ck & 7;
        const int sc = c ^ (r & 7);         // pre-swizzled global column
        const size_t xoff = (size_t)(row0 + r) * DIM + d0 + sc * 8;
        const size_t coff = (size_t)(code0 + r) * DIM + d0 + sc * 8;
        GLOAD16(Xh + xoff, XhS + cb * 8);
        GLOAD16(Xl + xoff, XlS + cb * 8);
        GLOAD16(Ch + coff, ChS + cb * 8);
        GLOAD16(Cl + coff, ClS + cb * 8);
      }
      __syncthreads();  // staging complete (vmcnt drained by barrier)
#pragma unroll
      for (int kk = 0; kk < 2; ++kk) {
        const int sl = ((kk * 4 + g16) ^ (l15 & 7)) * 8;  // swizzled slot
        int arow[4], brow[4];
#pragma unroll
        for (int m = 0; m < 4; ++m) arow[m] = (wr * 64 + m * 16 + l15) * 64 + sl;
#pragma unroll
        for (int n = 0; n < 4; ++n) brow[n] = (wc * 64 + n * 16 + l15) * 64 + sl;
        short8v ah[4], bh[4], bl[4], al[4];
#pragma unroll
        for (int m = 0; m < 4; ++m) ah[m] = *(const short8v*)(XhS + arow[m]);
#pragma unroll
        for (int n = 0; n < 4; ++n) bh[n] = *(const short8v*)(ChS + brow[n]);
#pragma unroll
        for (int m = 0; m < 4; ++m)
#pragma unroll
          for (int n = 0; n < 4; ++n)
            acc[m][n] = __builtin_amdgcn_mfma_f32_16x16x32_bf16(
                ah[m], bh[n], acc[m][n], 0, 0, 0);
#pragma unroll
        for (int n = 0; n < 4; ++n) bl[n] = *(const short8v*)(ClS + brow[n]);
#pragma unroll
        for (int m = 0; m < 4; ++m)
#pragma unroll
          for (int n = 0; n < 4; ++n)
            acc[m][n] = __builtin_amdgcn_mfma_f32_16x16x32_bf16(
                ah[m], bl[n], acc[m][n], 0, 0, 0);
#pragma unroll
        for (int m = 0; m < 4; ++m) al[m] = *(const short8v*)(XlS + arow[m]);
#pragma unroll
        for (int m = 0; m < 4; ++m)
#pragma unroll
          for (int n = 0; n < 4; ++n)
            acc[m][n] = __builtin_amdgcn_mfma_f32_16x16x32_bf16(
                al[m], bh[n], acc[m][n], 0, 0, 0);
      }
    }

    // per-tile argmin epilogue (replicate ref rounding exactly)
    float cs_r[4];
#pragma unroll
    for (int n = 0; n < 4; ++n) cs_r[n] = csq[code0 + wc * 64 + n * 16 + l15];
#pragma unroll
    for (int m = 0; m < 4; ++m)
#pragma unroll
      for (int n = 0; n < 4; ++n) {
        const int code = code0 + wc * 64 + n * 16 + l15;
#pragma unroll
        for (int r = 0; r < 4; ++r) {
          float dist = xsq_r[m][r] - 2.0f * acc[m][n][r];
          dist += cs_r[n];
          if (dist < best_d[m][r]) { best_d[m][r] = dist; best_i[m][r] = code; }
        }
      }
  }

  // 16-lane (code-dim) reduction with lowest-index tie-break
#pragma unroll
  for (int m = 0; m < 4; ++m)
#pragma unroll
    for (int r = 0; r < 4; ++r) {
      float d = best_d[m][r];
      int   bi = best_i[m][r];
#pragma unroll
      for (int off = 1; off < 16; off <<= 1) {
        float od = __shfl_xor(d, off, 64);
        int   oi = __shfl_xor(bi, off, 64);
        if (od < d || (od == d && oi < bi)) { d = od; bi = oi; }
      }
      if (l15 == 0) {
        const int tl = wr * 64 + m * 16 + g16 * 4 + r;
        red_d[wc][tl] = d;
        red_i[wc][tl] = bi;
      }
    }
  __syncthreads();
  if (tid < 128) {
    float da = red_d[0][tid], db = red_d[1][tid];
    int   ia = red_i[0][tid], ib = red_i[1][tid];
    bool take_b = (db < da) || (db == da && ib < ia);
    pd[blockIdx.y * TOKENS + row0 + tid] = take_b ? db : da;
    pi[blockIdx.y * TOKENS + row0 + tid] = (float)(take_b ? ib : ia);
  }
}

// ---------------------------------------------------------------------------
__global__ void merge_kernel(const float* __restrict__ pd,
                             const float* __restrict__ pi,
                             float* __restrict__ out_idx) {
  int t = blockIdx.x * blockDim.x + threadIdx.x;
  if (t >= TOKENS) return;
  float bd = pd[t];
  float bi = pi[t];
#pragma unroll
  for (int y = 1; y < CSPLIT; ++y) {
    float d = pd[y * TOKENS + t], ii = pi[y * TOKENS + t];
    if (d < bd || (d == bd && ii < bi)) { bd = d; bi = ii; }
  }
  out_idx[t] = bi;
}

__global__ void zero_kernel(float* __restrict__ p, int n) {
  int i = blockIdx.x * blockDim.x + threadIdx.x;
  if (i < n) p[i] = 0.0f;
}

__global__ void count_kernel(const float* __restrict__ idxf,
                             float* __restrict__ counts) {
  int t = blockIdx.x * blockDim.x + threadIdx.x;
  if (t < TOKENS) atomicAdd(&counts[(int)idxf[t]], 1.0f);
}

__global__ void ema_kernel(const float* __restrict__ cc,
                           const float* __restrict__ counts,
                           float* __restrict__ out) {
  int k = blockIdx.x * blockDim.x + threadIdx.x;
  if (k < KCODES) out[k] = 0.99f * cc[k] + 0.01f * counts[k];
}

__global__ void output_kernel(const float* __restrict__ X,
                              const float* __restrict__ CB,
                              const float* __restrict__ idxf,
                              float* __restrict__ out0,
                              float* __restrict__ out1) {
  int g = blockIdx.x * blockDim.x + threadIdx.x;  // float4 index
  if (g >= TOKENS * DIM / 4) return;
  int token = g >> 7;
  int idx = (int)idxf[token];
  float4 x4 = reinterpret_cast<const float4*>(X)[g];
  float4 q4 = reinterpret_cast<const float4*>(CB)[(size_t)idx * 128 + (g & 127)];
  float4 o0, o1;
  {
    float d;
    d = q4.x - x4.x; o0.x = x4.x + d; { float s = d * d; o1.x = s + 0.25f * s; }
    d = q4.y - x4.y; o0.y = x4.y + d; { float s = d * d; o1.y = s + 0.25f * s; }
    d = q4.z - x4.z; o0.z = x4.z + d; { float s = d * d; o1.z = s + 0.25f * s; }
    d = q4.w - x4.w; o0.w = x4.w + d; { float s = d * d; o1.w = s + 0.25f * s; }
  }
  reinterpret_cast<float4*>(out0)[g] = o0;
  reinterpret_cast<float4*>(out1)[g] = o1;
}

// ---------------------------------------------------------------------------
extern "C" void kernel_launch(void* const* d_in, const int* in_sizes, int n_in,
                              void* d_out, int out_size, void* d_ws,
                              size_t ws_size, hipStream_t stream) {
  const float* X  = (const float*)d_in[0];  // [32768, 512]
  const float* CB = (const float*)d_in[1];  // [4096, 512]
  const float* CC = (const float*)d_in[2];  // [4096]

  float* o = (float*)d_out;
  float* out0 = o;               // quantized_ste  16777216
  float* out1 = o + 16777216;    // quant_loss     16777216
  float* out2 = o + 33554432;    // nn_idx (float) 32768
  float* out3 = o + 33587200;    // codebook copy  2097152
  float* out4 = o + 35684352;    // new counts     4096

  // bf16 staging lives in the out0/out1 regions (128 MB), which are only
  // written by output_kernel at the very end.
  unsigned short* Xh = (unsigned short*)d_out;
  unsigned short* Xl = Xh + (size_t)TOKENS * DIM;
  unsigned short* Chp = Xl + (size_t)TOKENS * DIM;
  unsigned short* Clp = Chp + (size_t)KCODES * DIM;
  float* pd = (float*)(Clp + (size_t)KCODES * DIM);  // [CSPLIT][TOKENS]
  float* pi = pd + TOKENS * CSPLIT;                  // [CSPLIT][TOKENS]

  float* ws_xsq    = (float*)d_ws;          // 32768
  float* ws_csq    = ws_xsq + TOKENS;       // 4096
  float* ws_counts = ws_csq + KCODES;       // 4096

  split_kernel<<<TOKENS * DIM / 8 / 256, 256, 0, stream>>>(X, Xh, Xl,
                                                           TOKENS * DIM / 8);
  split_kernel<<<KCODES * DIM / 8 / 256, 256, 0, stream>>>(CB, Chp, Clp,
                                                           KCODES * DIM / 8);
  rowsumsq_kernel<<<TOKENS / 4, 256, 0, stream>>>(X, ws_xsq, TOKENS);
  rowsumsq_kernel<<<KCODES / 4, 256, 0, stream>>>(CB, ws_csq, KCODES);
  zero_kernel<<<(KCODES + 255) / 256, 256, 0, stream>>>(ws_counts, KCODES);

  dim3 grid(TOKENS / 128, CSPLIT);
  argmin_mfma_kernel<<<grid, 256, 0, stream>>>(Xh, Xl, Chp, Clp, ws_xsq,
                                               ws_csq, pd, pi);
  merge_kernel<<<TOKENS / 256, 256, 0, stream>>>(pd, pi, out2);

  count_kernel<<<TOKENS / 256, 256, 0, stream>>>(out2, ws_counts);
  ema_kernel<<<(KCODES + 255) / 256, 256, 0, stream>>>(CC, ws_counts, out4);
  output_kernel<<<(TOKENS * DIM / 4 + 255) / 256, 256, 0, stream>>>(
      X, CB, out2, out0, out1);
  hipMemcpyAsync(out3, CB, (size_t)KCODES * DIM * sizeof(float),
                 hipMemcpyDeviceToDevice, stream);
}